// Round 2
// baseline (1460.670 us; speedup 1.0000x reference)
//
#include <hip/hip_runtime.h>
#include <hip/hip_bf16.h>
#include <stdint.h>

// Problem constants (W8Linear): out[m][n] = sum_k x[m][k] * wq[n][k] * max_val[n]/127
constexpr int Mdim = 4 * 2048;   // 8192
constexpr int Kdim = 4096;
constexpr int Ndim = 11008;

constexpr int BM = 128;
constexpr int BN = 128;
constexpr int BK = 32;

typedef _Float16 f16x8 __attribute__((ext_vector_type(8)));
typedef _Float16 f16x4 __attribute__((ext_vector_type(4)));
typedef float    f32x4 __attribute__((ext_vector_type(4)));
typedef int      i32x4 __attribute__((ext_vector_type(4)));

// ---------------- converts: fp32 -> f16, int32 -> f16 (exact for |v|<=127) ----

__global__ __launch_bounds__(256) void cvt_f32_f16(const float* __restrict__ in,
                                                   _Float16* __restrict__ out,
                                                   int nvec8) {
  int idx = blockIdx.x * blockDim.x + threadIdx.x;
  int stride = gridDim.x * blockDim.x;
  for (int i = idx; i < nvec8; i += stride) {
    const f32x4* p = (const f32x4*)in + (size_t)i * 2;
    f32x4 a = p[0];
    f32x4 b = p[1];
    f16x8 h;
    h[0] = (_Float16)a[0]; h[1] = (_Float16)a[1];
    h[2] = (_Float16)a[2]; h[3] = (_Float16)a[3];
    h[4] = (_Float16)b[0]; h[5] = (_Float16)b[1];
    h[6] = (_Float16)b[2]; h[7] = (_Float16)b[3];
    ((f16x8*)out)[i] = h;
  }
}

__global__ __launch_bounds__(256) void cvt_i32_f16(const int* __restrict__ in,
                                                   _Float16* __restrict__ out,
                                                   int nvec8) {
  int idx = blockIdx.x * blockDim.x + threadIdx.x;
  int stride = gridDim.x * blockDim.x;
  for (int i = idx; i < nvec8; i += stride) {
    const i32x4* p = (const i32x4*)in + (size_t)i * 2;
    i32x4 a = p[0];
    i32x4 b = p[1];
    f16x8 h;
    h[0] = (_Float16)a[0]; h[1] = (_Float16)a[1];
    h[2] = (_Float16)a[2]; h[3] = (_Float16)a[3];
    h[4] = (_Float16)b[0]; h[5] = (_Float16)b[1];
    h[6] = (_Float16)b[2]; h[7] = (_Float16)b[3];
    ((f16x8*)out)[i] = h;
  }
}

// ---------------- async global->LDS, 16B per lane -----------------------------
// Dest discipline (m104/m108): HW writes wave-uniform base + lane*16. Our LDS
// byte addr is exactly chunkid*16 with chunkid = i*256 + t, so within a wave
// addresses are base + lane*16. Keep LDS layout linear (no padding).

__device__ __forceinline__ void gl_lds16(const _Float16* g, _Float16* l) {
  __builtin_amdgcn_global_load_lds(
      (const __attribute__((address_space(1))) unsigned int*)g,
      (__attribute__((address_space(3))) unsigned int*)l,
      16, 0, 0);
}

// ---------------- GEMM: 128x128 tile, BK=32, 4 waves (2x2), 16x16x32 f16 MFMA -
// FROM_WS=true : A,B are pre-converted f16 (linear [row][k] row-major, K contig)
// FROM_WS=false: A is fp32, B is int32; reg-staged with inline convert.

template <bool FROM_WS>
__global__ __launch_bounds__(256) void w8_gemm(const void* __restrict__ Ap,
                                               const void* __restrict__ Bp,
                                               const float* __restrict__ maxval,
                                               float* __restrict__ C) {
  __shared__ _Float16 As[BM][BK];  // 8 KiB
  __shared__ _Float16 Bs[BN][BK];  // 8 KiB

  const int nbn = Ndim / BN;              // 86
  const int nwg = (Mdim / BM) * nbn;      // 5504 (divisible by 8 -> swizzle bijective)
  const int cpx = nwg / 8;
  int bid = blockIdx.x;
  bid = (bid % 8) * cpx + (bid / 8);      // XCD-aware swizzle (T1)
  const int bm = bid / nbn;
  const int bn = bid % nbn;
  const int rowBase = bm * BM;
  const int colBase = bn * BN;

  const int t = threadIdx.x;
  const int lane = t & 63;
  const int wid = t >> 6;       // 0..3
  const int wr = wid >> 1;      // wave row 0..1 (owns 64 output rows)
  const int wc = wid & 1;       // wave col 0..1 (owns 64 output cols)
  const int lrow = lane & 15;   // fragment row/col index
  const int kgrp = lane >> 4;   // 0..3 k-chunk

  f32x4 acc[4][4] = {};

  for (int k0 = 0; k0 < Kdim; k0 += BK) {
    __syncthreads();  // protect LDS from previous iteration's readers
    if constexpr (FROM_WS) {
      const _Float16* A  = (const _Float16*)Ap;
      const _Float16* Bw = (const _Float16*)Bp;
#pragma unroll
      for (int i = 0; i < 2; ++i) {
        int c = i * 256 + t;        // 16-byte chunk id within tile
        int r = c >> 2;             // tile row (64 B per row)
        int ce = (c & 3) * 8;       // element offset in row
        gl_lds16(A  + (size_t)(rowBase + r) * Kdim + k0 + ce, &As[r][ce]);
        gl_lds16(Bw + (size_t)(colBase + r) * Kdim + k0 + ce, &Bs[r][ce]);
      }
    } else {
      const float* A  = (const float*)Ap;
      const int*   Bw = (const int*)Bp;
#pragma unroll
      for (int i = 0; i < 4; ++i) {
        int c = i * 256 + t;        // 4-element chunk id
        int r = c >> 3;
        int ce = (c & 7) * 4;
        f32x4 av = *(const f32x4*)(A  + (size_t)(rowBase + r) * Kdim + k0 + ce);
        i32x4 bv = *(const i32x4*)(Bw + (size_t)(colBase + r) * Kdim + k0 + ce);
        f16x4 ah, bh;
#pragma unroll
        for (int j = 0; j < 4; ++j) {
          ah[j] = (_Float16)av[j];
          bh[j] = (_Float16)bv[j];
        }
        *(f16x4*)&As[r][ce] = ah;
        *(f16x4*)&Bs[r][ce] = bh;
      }
    }
    __syncthreads();  // staging visible (compiler drains vmcnt/lgkmcnt)

    f16x8 a[4], b[4];
#pragma unroll
    for (int m = 0; m < 4; ++m)
      a[m] = *(const f16x8*)&As[wr * 64 + m * 16 + lrow][kgrp * 8];
#pragma unroll
    for (int n = 0; n < 4; ++n)
      b[n] = *(const f16x8*)&Bs[wc * 64 + n * 16 + lrow][kgrp * 8];
#pragma unroll
    for (int m = 0; m < 4; ++m)
#pragma unroll
      for (int n = 0; n < 4; ++n)
        acc[m][n] = __builtin_amdgcn_mfma_f32_16x16x32_f16(a[m], b[n], acc[m][n], 0, 0, 0);
  }

  // Epilogue: C/D layout col=lane&15, row=(lane>>4)*4+reg (m89-verified).
  // Scale is per output COLUMN n: max_val[n]/127.
  float s[4];
#pragma unroll
  for (int n = 0; n < 4; ++n)
    s[n] = maxval[colBase + wc * 64 + n * 16 + lrow] * (1.0f / 127.0f);
#pragma unroll
  for (int m = 0; m < 4; ++m) {
#pragma unroll
    for (int j = 0; j < 4; ++j) {
      int row = rowBase + wr * 64 + m * 16 + kgrp * 4 + j;
      float* cp = C + (size_t)row * Ndim + colBase + wc * 64 + lrow;
#pragma unroll
      for (int n = 0; n < 4; ++n)
        cp[n * 16] = acc[m][n][j] * s[n];
    }
  }
}

// ---------------- launch ------------------------------------------------------

extern "C" void kernel_launch(void* const* d_in, const int* in_sizes, int n_in,
                              void* d_out, int out_size, void* d_ws, size_t ws_size,
                              hipStream_t stream) {
  const float* x  = (const float*)d_in[0];   // [8192, 4096] fp32
  const int*   wq = (const int*)d_in[1];     // [11008, 4096] int32
  const float* mx = (const float*)d_in[2];   // [11008] fp32
  float* out = (float*)d_out;                // [8192, 11008] fp32

  const size_t xh_bytes = (size_t)Mdim * Kdim * sizeof(_Float16);  // 64 MiB
  const size_t wh_bytes = (size_t)Ndim * Kdim * sizeof(_Float16);  // 86 MiB
  const int nblocks = (Mdim / BM) * (Ndim / BN);                   // 5504

  if (ws_size >= xh_bytes + wh_bytes) {
    _Float16* xh = (_Float16*)d_ws;
    _Float16* wh = (_Float16*)((char*)d_ws + xh_bytes);
    cvt_f32_f16<<<2048, 256, 0, stream>>>(x, xh, Mdim * Kdim / 8);
    cvt_i32_f16<<<2048, 256, 0, stream>>>(wq, wh, Ndim * Kdim / 8);
    w8_gemm<true><<<nblocks, 256, 0, stream>>>(xh, wh, mx, out);
  } else {
    // workspace too small for f16 mirrors: reg-staged convert-in-GEMM fallback
    w8_gemm<false><<<nblocks, 256, 0, stream>>>(x, wq, mx, out);
  }
}